// Round 5
// baseline (374.432 us; speedup 1.0000x reference)
//
#include <hip/hip_runtime.h>
#include <math.h>

// ---- problem constants ----
#define BB 32
#define LL 128
#define HSZ 512
#define PP 12
#define MM 1024
#define VV 50000
#define DD 128
#define CLEN 16
#define NTOT 4096           // B*L
#define LISTCAP 512

// GEMM tiling (r9): 32x64 tile, BK=32, 2x4 acc/thread, f64 LDS staging.
// Combines r2's no-cvt inner loop (least VALU work) with r4's RT=32 grid
// (6 blocks/CU). LDS = 25.7KB -> all 6 resident -> 24 waves/CU.
#define RT5 32
#define CT5 64
#define BK5 32
// cpy tiling
#define CPB 16              // rows per cpy block

// output offsets (floats)
#define OFF_WORD  0
#define OFF_CHAR  4096
#define OFF_PSR   69632
#define OFF_ATK   593920
#define OFF_OBFM  1118208
#define OFF_CPYM  1122304
#define OFF_PRIM  1126400
#define OFF_CLOSS 1130496
#define OFF_ELOSS 1130497

// ws layout: floats [0..11]=ent partials [12]=closs ; ints [16..27]=cnt ;
// ints [64..6207]=rowlist ; floats [6656..14847]=scbuf ; floats [16384..]=logits
#define WS_SC_OFF     6656
#define WS_LOGITS_OFF 16384

// ---- CR-f32 transcendentals via double libm (bit-critical gate path) ----
__device__ __forceinline__ float EXP32(float x){ return (float)exp((double)x); }
__device__ __forceinline__ float LOG32(float x){ return (float)log((double)x); }

// ---- JAX threefry2x32 (20 rounds) — verified vs known-answer vector ----
__device__ __forceinline__ unsigned rotl32(unsigned x, int r){ return (x<<r)|(x>>(32-r)); }
__device__ __forceinline__ void tf2x32(unsigned k0, unsigned k1, unsigned x0, unsigned x1,
                                       unsigned &o0, unsigned &o1){
  unsigned ks2 = k0 ^ k1 ^ 0x1BD11BDAu;
  x0 += k0; x1 += k1;
  x0+=x1; x1=rotl32(x1,13); x1^=x0;
  x0+=x1; x1=rotl32(x1,15); x1^=x0;
  x0+=x1; x1=rotl32(x1,26); x1^=x0;
  x0+=x1; x1=rotl32(x1, 6); x1^=x0;
  x0+=k1; x1+=ks2+1u;
  x0+=x1; x1=rotl32(x1,17); x1^=x0;
  x0+=x1; x1=rotl32(x1,29); x1^=x0;
  x0+=x1; x1=rotl32(x1,16); x1^=x0;
  x0+=x1; x1=rotl32(x1,24); x1^=x0;
  x0+=ks2; x1+=k0+2u;
  x0+=x1; x1=rotl32(x1,13); x1^=x0;
  x0+=x1; x1=rotl32(x1,15); x1^=x0;
  x0+=x1; x1=rotl32(x1,26); x1^=x0;
  x0+=x1; x1=rotl32(x1, 6); x1^=x0;
  x0+=k0; x1+=k1+3u;
  x0+=x1; x1=rotl32(x1,17); x1^=x0;
  x0+=x1; x1=rotl32(x1,29); x1^=x0;
  x0+=x1; x1=rotl32(x1,16); x1^=x0;
  x0+=x1; x1=rotl32(x1,24); x1^=x0;
  x0+=k1; x1+=ks2+4u;
  x0+=x1; x1=rotl32(x1,13); x1^=x0;
  x0+=x1; x1=rotl32(x1,15); x1^=x0;
  x0+=x1; x1=rotl32(x1,26); x1^=x0;
  x0+=x1; x1=rotl32(x1, 6); x1^=x0;
  x0+=ks2; x1+=k0+5u;
  o0=x0; o1=x1;
}

// jax_threefry_partitionable=True random_bits: count (0,e), output o0^o1
__device__ __forceinline__ unsigned tf_bits32(unsigned k0, unsigned k1, unsigned e){
  unsigned o0, o1; tf2x32(k0, k1, 0u, e, o0, o1); return o0 ^ o1;
}

__device__ __forceinline__ float bits_to_unif(unsigned bits){
  const float lo = 1e-6f;
  const float hi = (float)(1.0 - 1e-6);
  const float span = hi - lo;
  unsigned fb = (bits >> 9) | 0x3f800000u;
  float f = __fsub_rn(__uint_as_float(fb), 1.0f);
  float r = __fadd_rn(__fmul_rn(f, span), lo);
  return fmaxf(lo, r);
}

// exact (CR) gumbel — cpy gate only (bit-critical: decides c in {1,1-2^-24})
__device__ __forceinline__ float gumbel_exact(unsigned bits){
  float u = bits_to_unif(bits);
  float v = -LOG32(u);
  return -LOG32(v);
}
// fast (ocml f32) gumbel — finalize argmax path (proven r5)
__device__ __forceinline__ float gumbel_fast(unsigned bits){
  float u = bits_to_unif(bits);
  float v = -logf(u);
  return -logf(v);
}

// ---- the copy-gate chain (CR double-libm path, bit-identical r2-r5) ----
__device__ __forceinline__ void gate_chain(int n, int pos, int msk,
                                           float p0f, float p1f,
                                           const float* __restrict__ cb2,
                                           float* __restrict__ sc0,
                                           float* __restrict__ sc1,
                                           float* __restrict__ closs)
{
  const bool ispri = (pos < 4);
  float pc0 = __fadd_rn(p0f, cb2[0]);
  float pc1 = __fadd_rn(p1f, cb2[1]);
  float m2  = fmaxf(pc0, pc1);
  float s0  = __fsub_rn(pc0, m2), s1 = __fsub_rn(pc1, m2);
  float se  = __fadd_rn(EXP32(s0), EXP32(s1));
  float lse = LOG32(se);
  float q0  = __fsub_rn(s0, lse), q1 = __fsub_rn(s1, lse);
  if (ispri){ q0 = 0.0f; q1 = 1.0f; }

  unsigned k90, k91; tf2x32(0u, 42u, 0u, 999u, k90, k91);
  float g0 = gumbel_exact(tf_bits32(k90, k91, (unsigned)(2*n)));
  float g1 = gumbel_exact(tf_bits32(k90, k91, (unsigned)(2*n + 1)));

  float x0 = __fadd_rn(q0, g0), x1 = __fadd_rn(q1, g1);
  float mmv = fmaxf(x0, x1);
  float ex0 = EXP32(__fsub_rn(x0, mmv));
  float ex1 = EXP32(__fsub_rn(x1, mmv));
  float ssum = __fadd_rn(ex0, ex1);
  float y0 = __fdiv_rn(ex0, ssum), y1 = __fdiv_rn(ex1, ssum);
  int   idx2 = (y1 > y0) ? 1 : 0;
  float ysel = idx2 ? y1 : y0;
  float c    = __fsub_rn(__fadd_rn(1.0f, ysel), ysel);
  *sc0 = (idx2 == 0) ? c : 0.0f;
  *sc1 = (idx2 == 1) ? c : 0.0f;

  float m3 = fmaxf(q0, q1);
  float t0 = __fsub_rn(q0, m3), t1 = __fsub_rn(q1, m3);
  float se2 = __fadd_rn(EXP32(t0), EXP32(t1));
  float l21 = __fsub_rn(t1, LOG32(se2));
  if (msk != 0 && (n & (LL-1)) != 0) atomicAdd(closs, l21);
}

// ---------- Kernel A: bucket build + tiled cpy MLP/gate (16 rows/block) ----------
__global__ __launch_bounds__(256)
void cpy_build_kernel(const float* __restrict__ ctx, const float* __restrict__ cW1,
                      const float* __restrict__ cb1, const float* __restrict__ cW2,
                      const float* __restrict__ cb2, const int* __restrict__ inp_pos,
                      const int* __restrict__ inp_mask, int* __restrict__ cntg,
                      int* __restrict__ rowlist, float* __restrict__ scbuf,
                      float* __restrict__ ws)
{
  const int n0 = blockIdx.x * CPB;
  const int t = threadIdx.x;

  if (t < CPB){
    int n = n0 + t;
    int p = inp_pos[n];
    if (p < PP){
      int slot = atomicAdd(&cntg[p], 1);
      if (slot < LISTCAP) rowlist[p*LISTCAP + slot] = n;
    }
  }

  __shared__ float W1s[64][68];     // [k][o], padded
  __shared__ float Cs[CPB][68];     // [row][k], padded

  const int r  = t >> 4;            // 0..15  (row)
  const int og = (t & 15) * 4;      // output group of 4
  double acc[4] = {0.0, 0.0, 0.0, 0.0};

  for (int k0 = 0; k0 < HSZ; k0 += 64){
    #pragma unroll
    for (int i = 0; i < 4; ++i){    // W1 chunk 64k x 64o
      int s = t + i*256;
      int kk = s >> 4, q = s & 15;
      float4 v = *(const float4*)(cW1 + (size_t)(k0+kk)*64 + q*4);
      *(float4*)&W1s[kk][q*4] = v;
    }
    {                               // ctx chunk 16 rows x 64 k
      int rr = t >> 4, q = t & 15;
      float4 v = *(const float4*)(ctx + (size_t)(n0+rr)*HSZ + k0 + q*4);
      *(float4*)&Cs[rr][q*4] = v;
    }
    __syncthreads();
    #pragma unroll 4
    for (int kk = 0; kk < 64; ++kk){
      double c = (double)Cs[r][kk];
      acc[0] += c * (double)W1s[kk][og+0];
      acc[1] += c * (double)W1s[kk][og+1];
      acc[2] += c * (double)W1s[kk][og+2];
      acc[3] += c * (double)W1s[kk][og+3];
    }
    __syncthreads();
  }

  // bias + relu + W2 partials, reduce across the 16 lanes of the row
  double p0 = 0.0, p1 = 0.0;
  #pragma unroll
  for (int j = 0; j < 4; ++j){
    float hv = __fadd_rn((float)acc[j], cb1[og+j]);
    hv = hv > 0.f ? hv : 0.f;
    double hd = (double)hv;
    p0 += hd * (double)cW2[2*(og+j)+0];
    p1 += hd * (double)cW2[2*(og+j)+1];
  }
  #pragma unroll
  for (int off = 1; off < 16; off <<= 1){
    p0 += __shfl_xor(p0, off);
    p1 += __shfl_xor(p1, off);
  }

  if ((t & 15) == 0){
    const int n = n0 + r;
    float c0v, c1v;
    gate_chain(n, inp_pos[n], inp_mask[n], (float)p0, (float)p1, cb2,
               &c0v, &c1v, ws + 12);
    scbuf[2*n + 0] = c0v;
    scbuf[2*n + 1] = c1v;
  }
}

// ---------- Kernel B: gathered GEMM 32x64, f64 acc, strict k order ----------
// r9: f64 LDS staging (exact f32->f64 cvt at staging, r2-proven numerics) +
// RT=32 small tile (r4-proven grid/occupancy). Inner loop: 4 LDS reads +
// 8 f64 FMA per kk, zero cvt. Accumulation per acc element is k=0..511
// sequential with identical statement forms => bit-identical output.
__global__ __launch_bounds__(256)
void gemm_kernel(const float* __restrict__ ctx, const float* __restrict__ dec_W,
                 const int* __restrict__ cntg, const int* __restrict__ rowlist,
                 float* __restrict__ logits)
{
  const int p  = blockIdx.z;
  const int c0 = blockIdx.x * CT5;
  const int r0 = blockIdx.y * RT5;
  const int cnt0 = cntg[p];
  const int cnt  = cnt0 < LISTCAP ? cnt0 : LISTCAP;
  if (r0 >= cnt) return;
  const int t = threadIdx.x;

  __shared__ double As[RT5][BK5+2];   // pitch 34: A-reads conflict-free (r2)
  __shared__ double Bs[BK5][CT5+2];   // pitch 66: B-reads 4-way (1.58x on 2 instrs)
  __shared__ int    rid_s[RT5];

  if (t < RT5){
    int rr = r0 + t;
    rid_s[t] = rowlist[p*LISTCAP + (rr < cnt ? rr : cnt-1)];
  }
  __syncthreads();

  const int tr = t >> 4, tc = t & 15;   // tr 0..15 -> rows tr*2..tr*2+1
  double acc[2][4];
  #pragma unroll
  for (int i = 0; i < 2; ++i)
    #pragma unroll
    for (int j = 0; j < 4; ++j) acc[i][j] = 0.0;

  const float* Wp = dec_W + (size_t)p * HSZ * MM;

  for (int k0 = 0; k0 < HSZ; k0 += BK5){
    {                               // A: 32 rows x 32 k, 1 float4/thread -> f64
      int rr = t >> 3, q = t & 7;
      float4 v = *(const float4*)(ctx + (size_t)rid_s[rr]*HSZ + k0 + q*4);
      double2 d0; d0.x = (double)v.x; d0.y = (double)v.y;
      double2 d1; d1.x = (double)v.z; d1.y = (double)v.w;
      *(double2*)&As[rr][q*4 + 0] = d0;   // (rr*34+q*4) even -> 16B aligned
      *(double2*)&As[rr][q*4 + 2] = d1;
    }
    #pragma unroll
    for (int i = 0; i < 2; ++i){    // B: 32 k x 64 c, 2 float4/thread -> f64
      int s = t + i*256;
      int kk = s >> 4, q = s & 15;
      float4 v = *(const float4*)(Wp + (size_t)(k0+kk)*MM + c0 + q*4);
      double2 d0; d0.x = (double)v.x; d0.y = (double)v.y;
      double2 d1; d1.x = (double)v.z; d1.y = (double)v.w;
      *(double2*)&Bs[kk][q*4 + 0] = d0;   // (kk*66+q*4) even -> 16B aligned
      *(double2*)&Bs[kk][q*4 + 2] = d1;
    }
    __syncthreads();
    #pragma unroll 4
    for (int kk = 0; kk < BK5; ++kk){
      double b0 = Bs[kk][tc*4+0];
      double b1 = Bs[kk][tc*4+1];
      double b2 = Bs[kk][tc*4+2];
      double b3 = Bs[kk][tc*4+3];
      double a0 = As[tr*2+0][kk];
      double a1 = As[tr*2+1][kk];
      acc[0][0]+=a0*b0; acc[0][1]+=a0*b1; acc[0][2]+=a0*b2; acc[0][3]+=a0*b3;
      acc[1][0]+=a1*b0; acc[1][1]+=a1*b1; acc[1][2]+=a1*b2; acc[1][3]+=a1*b3;
    }
    __syncthreads();
  }

  #pragma unroll
  for (int i = 0; i < 2; ++i){
    int rr = r0 + tr*2 + i;
    if (rr < cnt){
      int rg = rid_s[tr*2 + i];
      float4 o;
      o.x=(float)acc[i][0]; o.y=(float)acc[i][1]; o.z=(float)acc[i][2]; o.w=(float)acc[i][3];
      *(float4*)(logits + (size_t)rg*MM + c0 + tc*4) = o;
    }
  }
}

// ---------- Kernel C: finalize, ONE WAVE PER ROW (no __syncthreads) ----------
__global__ __launch_bounds__(256)
void finalize_kernel(const float* __restrict__ dec_b,
                     const float* __restrict__ psr_w, const float* __restrict__ atk_w,
                     const int* __restrict__ inp_word, const int* __restrict__ inp_pos,
                     const int* __restrict__ inp_mask, const int* __restrict__ words,
                     const int* __restrict__ lut, const float* __restrict__ logitsbuf,
                     const float* __restrict__ scbuf,
                     float* __restrict__ out, float* __restrict__ ws)
{
  const int wid = threadIdx.x >> 6, lane = threadIdx.x & 63;
  const int n = blockIdx.x * 4 + wid;

  const int  pos   = inp_pos[n];
  const int  word  = inp_word[n];
  const int  msk   = inp_mask[n];
  const bool isobf = (pos < PP);
  const bool ispri = (pos < 4);
  const float c0 = scbuf[2*n + 0];
  const float c1 = scbuf[2*n + 1];

  int bi = 0;
  if (isobf){
    // load 16 logits per lane (coalesced float4 per iter), add bias
    float l[16];
    float lm = -3.4e38f;
    #pragma unroll
    for (int it = 0; it < 4; ++it){
      int m = it*256 + lane*4;
      float4 lg = *(const float4*)(logitsbuf + (size_t)n*MM + m);
      float4 bq = *(const float4*)(dec_b + (size_t)pos*MM + m);
      l[it*4+0] = __fadd_rn(lg.x, bq.x);
      l[it*4+1] = __fadd_rn(lg.y, bq.y);
      l[it*4+2] = __fadd_rn(lg.z, bq.z);
      l[it*4+3] = __fadd_rn(lg.w, bq.w);
      lm = fmaxf(lm, fmaxf(fmaxf(l[it*4+0], l[it*4+1]), fmaxf(l[it*4+2], l[it*4+3])));
    }
    #pragma unroll
    for (int off = 32; off > 0; off >>= 1) lm = fmaxf(lm, __shfl_xor(lm, off));
    const float xmax = lm;

    float e[16];
    double ds = 0.0;
    #pragma unroll
    for (int j = 0; j < 16; ++j){
      e[j] = expf(__fsub_rn(l[j], xmax));
      ds += (double)e[j];
    }
    #pragma unroll
    for (int off = 32; off > 0; off >>= 1) ds += __shfl_xor(ds, off);
    const double se = ds;
    const float lse = logf((float)se);
    const double inv_se = 1.0 / se;

    unsigned kp0, kp1; tf2x32(0u, 42u, 0u, (unsigned)pos, kp0, kp1);
    float best = -3.4e38f; double es = 0.0;
    #pragma unroll
    for (int it = 0; it < 4; ++it){
      #pragma unroll
      for (int j = 0; j < 4; ++j){
        int m = it*256 + lane*4 + j;
        float sh = __fsub_rn(l[it*4+j], xmax);
        float lp = __fsub_rn(sh, lse);
        es += (double)(-lp) * ((double)e[it*4+j] * inv_se);
        float g = gumbel_fast(tf_bits32(kp0, kp1, (unsigned)(n*MM + m)));
        float sv = __fadd_rn(lp, g);
        if (sv > best){ best = sv; bi = m; }
      }
    }
    #pragma unroll
    for (int off = 32; off > 0; off >>= 1){
      float ov = __shfl_xor(best, off);
      int   oi = __shfl_xor(bi,   off);
      if (ov > best || (ov == best && oi < bi)){ best = ov; bi = oi; }
      es += __shfl_xor(es, off);
    }
    if (lane == 0) atomicAdd(ws + pos, (float)es);
  }

  // ---------- epilogue (per wave = per row) ----------
  const int obf_word = isobf ? words[pos*MM + bi] : word;
  float of = __fadd_rn(__fmul_rn((float)word, c0), __fmul_rn((float)obf_word, c1));
  int ow = (int)of;
  if (lane == 0){
    out[OFF_WORD + n] = (float)ow;
    bool cpym = (c0 == 1.0f) && (msk != 0);
    out[OFF_CPYM + n] = cpym ? 1.f : 0.f;
    out[OFF_OBFM + n] = (isobf && !cpym) ? 1.f : 0.f;
    out[OFF_PRIM + n] = ispri ? 1.f : 0.f;
  }
  if (lane < CLEN)
    out[OFF_CHAR + (size_t)n*CLEN + lane] = (float)lut[(size_t)ow*CLEN + lane];
  #pragma unroll
  for (int rep = 0; rep < 2; ++rep){
    int j = lane + rep*64;
    float po = psr_w[(size_t)word*DD + j];
    float pb = isobf ? psr_w[(size_t)obf_word*DD + j] : po;
    out[OFF_PSR + (size_t)n*DD + j] = __fadd_rn(__fmul_rn(po, c0), __fmul_rn(pb, c1));
    float ao = atk_w[(size_t)word*DD + j];
    float ab = isobf ? atk_w[(size_t)obf_word*DD + j] : ao;
    out[OFF_ATK + (size_t)n*DD + j] = __fadd_rn(__fmul_rn(ao, c0), __fmul_rn(ab, c1));
  }
}

// ---------- losses ----------
__global__ __launch_bounds__(256)
void fin_kernel(const int* __restrict__ inp_pos, const int* __restrict__ inp_mask,
                const float* __restrict__ ws, float* __restrict__ out)
{
  __shared__ int cnt[PP];
  __shared__ int nr;
  int t = threadIdx.x;
  if (t < PP) cnt[t] = 0;
  if (t == 0) nr = 0;
  __syncthreads();
  int ln = 0;
  for (int n = t; n < NTOT; n += 256){
    int p = inp_pos[n];
    if (p < PP) atomicAdd(&cnt[p], 1);
    if (inp_mask[n] != 0 && (n & (LL-1)) != 0) ln++;
  }
  atomicAdd(&nr, ln);
  __syncthreads();
  if (t == 0){
    float ent = 0.f;
    for (int p = 0; p < PP; ++p){
      int c = cnt[p];
      if (c > 0){
        int denom = c * MM; if (denom < 1) denom = 1;
        ent = __fadd_rn(ent, __fdiv_rn(ws[p], (float)denom));
      }
    }
    out[OFF_ELOSS] = -ent;
    int nrc = nr; if (nrc < 1) nrc = 1;
    out[OFF_CLOSS] = -__fdiv_rn(ws[12], (float)nrc);
  }
}

// ---------- monolithic fallback (r2, proven) for tiny ws ----------
__global__ __launch_bounds__(256)
void row_kernel_mono(const float* __restrict__ ctx, const float* __restrict__ dec_W,
                const float* __restrict__ dec_b, const float* __restrict__ psr_w,
                const float* __restrict__ atk_w, const float* __restrict__ cW1,
                const float* __restrict__ cb1, const float* __restrict__ cW2,
                const float* __restrict__ cb2, const int* __restrict__ inp_word,
                const int* __restrict__ inp_pos, const int* __restrict__ inp_mask,
                const int* __restrict__ words, const int* __restrict__ lut,
                float* __restrict__ out, float* __restrict__ ws)
{
  const int n = blockIdx.x;
  const int t = threadIdx.x;

  __shared__ float  ctx_s[HSZ];
  __shared__ float  logit_s[MM];
  __shared__ float  h_s[64];
  __shared__ double redd[256];
  __shared__ float  redf[256];
  __shared__ int    redi[256];
  __shared__ float  sc[2];
  __shared__ int    si[1];

  for (int k = t; k < HSZ; k += 256) ctx_s[k] = ctx[(size_t)n*HSZ + k];
  __syncthreads();

  const int  pos   = inp_pos[n];
  const int  word  = inp_word[n];
  const int  msk   = inp_mask[n];
  const bool isobf = (pos < PP);
  const bool ispri = (pos < 4);

  if (t < 64){
    double acc = 0.0;
    for (int k = 0; k < HSZ; ++k) acc += (double)ctx_s[k] * (double)cW1[k*64 + t];
    float hv = __fadd_rn((float)acc, cb1[t]);
    h_s[t] = hv > 0.f ? hv : 0.f;
  }
  __syncthreads();

  if (t == 0){
    double a0 = 0.0, a1 = 0.0;
    for (int k = 0; k < 64; ++k){
      double hv = (double)h_s[k];
      a0 += hv * (double)cW2[k*2 + 0];
      a1 += hv * (double)cW2[k*2 + 1];
    }
    float c0v, c1v;
    gate_chain(n, pos, msk, (float)a0, (float)a1, cb2, &c0v, &c1v, ws + 12);
    sc[0] = c0v; sc[1] = c1v;
  }

  if (isobf){
    const float4* W4 = (const float4*)(dec_W + (size_t)pos * HSZ * MM);
    double a0=0.0, a1=0.0, a2=0.0, a3=0.0;
    for (int k = 0; k < HSZ; ++k){
      double c = (double)ctx_s[k];
      float4 w = W4[(size_t)k*256 + t];
      a0 += c*(double)w.x; a1 += c*(double)w.y; a2 += c*(double)w.z; a3 += c*(double)w.w;
    }
    const float* bp = dec_b + (size_t)pos * MM;
    const int m0 = 4*t;
    logit_s[m0+0] = __fadd_rn((float)a0, bp[m0+0]);
    logit_s[m0+1] = __fadd_rn((float)a1, bp[m0+1]);
    logit_s[m0+2] = __fadd_rn((float)a2, bp[m0+2]);
    logit_s[m0+3] = __fadd_rn((float)a3, bp[m0+3]);
    __syncthreads();

    float lm = logit_s[m0];
    lm = fmaxf(lm, logit_s[m0+1]); lm = fmaxf(lm, logit_s[m0+2]); lm = fmaxf(lm, logit_s[m0+3]);
    redf[t] = lm; __syncthreads();
    for (int s = 128; s > 0; s >>= 1){ if (t < s) redf[t] = fmaxf(redf[t], redf[t+s]); __syncthreads(); }
    const float xmax = redf[0];
    __syncthreads();

    double dsm = 0.0;
    for (int j = 0; j < 4; ++j)
      dsm += (double)EXP32(__fsub_rn(logit_s[m0+j], xmax));
    redd[t] = dsm; __syncthreads();
    for (int s = 128; s > 0; s >>= 1){ if (t < s) redd[t] += redd[t+s]; __syncthreads(); }
    const float lse = LOG32((float)redd[0]);
    __syncthreads();

    unsigned kp0, kp1; tf2x32(0u, 42u, 0u, (unsigned)pos, kp0, kp1);
    float best = -3.4e38f; int bi = 0; double es = 0.0;
    for (int j = 0; j < 4; ++j){
      int m = m0 + j;
      float sh = __fsub_rn(logit_s[m], xmax);
      float lp = __fsub_rn(sh, lse);
      float ex = EXP32(lp);
      es += (double)__fmul_rn(-lp, ex);
      float g = gumbel_exact(tf_bits32(kp0, kp1, (unsigned)(n*MM + m)));
      float sv = __fadd_rn(lp, g);
      if (sv > best){ best = sv; bi = m; }
    }
    redf[t] = best; redi[t] = bi; redd[t] = es; __syncthreads();
    for (int s = 128; s > 0; s >>= 1){
      if (t < s){
        float v2 = redf[t+s]; int i2 = redi[t+s];
        if (v2 > redf[t] || (v2 == redf[t] && i2 < redi[t])){ redf[t] = v2; redi[t] = i2; }
        redd[t] += redd[t+s];
      }
      __syncthreads();
    }
    if (t == 0){ si[0] = redi[0]; atomicAdd(ws + pos, (float)redd[0]); }
    __syncthreads();
  } else {
    __syncthreads();
  }

  const int   idx = isobf ? si[0] : 0;
  const float c0 = sc[0], c1 = sc[1];
  const int   obf_word = isobf ? words[pos*MM + idx] : word;

  if (t == 0){
    float of = __fadd_rn(__fmul_rn((float)word, c0), __fmul_rn((float)obf_word, c1));
    int ow = (int)of;
    out[OFF_WORD + n] = (float)ow;
    bool cpym = (c0 == 1.0f) && (msk != 0);
    out[OFF_CPYM + n] = cpym ? 1.f : 0.f;
    out[OFF_OBFM + n] = (isobf && !cpym) ? 1.f : 0.f;
    out[OFF_PRIM + n] = ispri ? 1.f : 0.f;
    #pragma unroll
    for (int j = 0; j < CLEN; ++j)
      out[OFF_CHAR + (size_t)n*CLEN + j] = (float)lut[(size_t)ow*CLEN + j];
  }
  if (t < DD){
    float po = psr_w[(size_t)word*DD + t];
    float pb = isobf ? psr_w[(size_t)obf_word*DD + t] : po;
    out[OFF_PSR + (size_t)n*DD + t] = __fadd_rn(__fmul_rn(po, c0), __fmul_rn(pb, c1));
    float ao = atk_w[(size_t)word*DD + t];
    float ab = isobf ? atk_w[(size_t)obf_word*DD + t] : ao;
    out[OFF_ATK + (size_t)n*DD + t] = __fadd_rn(__fmul_rn(ao, c0), __fmul_rn(ab, c1));
  }
}

extern "C" void kernel_launch(void* const* d_in, const int* in_sizes, int n_in,
                              void* d_out, int out_size, void* d_ws, size_t ws_size,
                              hipStream_t stream)
{
  const float* ctx      = (const float*)d_in[0];
  const float* dec_W    = (const float*)d_in[1];
  const float* dec_b    = (const float*)d_in[2];
  const float* psr_w    = (const float*)d_in[3];
  const float* atk_w    = (const float*)d_in[4];
  const float* cW1      = (const float*)d_in[5];
  const float* cb1      = (const float*)d_in[6];
  const float* cW2      = (const float*)d_in[7];
  const float* cb2      = (const float*)d_in[8];
  const int*   inp_word = (const int*)d_in[9];
  const int*   inp_pos  = (const int*)d_in[10];
  const int*   inp_mask = (const int*)d_in[11];
  const int*   words    = (const int*)d_in[12];
  const int*   lut      = (const int*)d_in[13];
  float* out = (float*)d_out;
  float* ws  = (float*)d_ws;

  const size_t need = ((size_t)WS_LOGITS_OFF + (size_t)NTOT*MM) * 4;

  hipMemsetAsync(ws, 0, 512, stream);   // ent/closs floats + cnt ints

  if (ws_size >= need){
    int*   cntg      = (int*)ws + 16;
    int*   rowlist   = (int*)ws + 64;
    float* scbuf     = ws + WS_SC_OFF;
    float* logitsbuf = ws + WS_LOGITS_OFF;
    cpy_build_kernel<<<NTOT/CPB, 256, 0, stream>>>(ctx, cW1, cb1, cW2, cb2,
                                                   inp_pos, inp_mask, cntg, rowlist,
                                                   scbuf, ws);
    gemm_kernel<<<dim3(MM/CT5, LISTCAP/RT5, PP), 256, 0, stream>>>(ctx, dec_W, cntg,
                                                                   rowlist, logitsbuf);
    finalize_kernel<<<NTOT/4, 256, 0, stream>>>(dec_b, psr_w, atk_w,
                                                inp_word, inp_pos, inp_mask, words, lut,
                                                logitsbuf, scbuf, out, ws);
  } else {
    row_kernel_mono<<<NTOT, 256, 0, stream>>>(ctx, dec_W, dec_b, psr_w, atk_w,
                                              cW1, cb1, cW2, cb2,
                                              inp_word, inp_pos, inp_mask, words, lut,
                                              out, ws);
  }
  fin_kernel<<<1, 256, 0, stream>>>(inp_pos, inp_mask, ws, out);
}

// Round 6
// 334.956 us; speedup vs baseline: 1.1179x; 1.1179x over previous
//
#include <hip/hip_runtime.h>
#include <math.h>

// ---- problem constants ----
#define BB 32
#define LL 128
#define HSZ 512
#define PP 12
#define MM 1024
#define VV 50000
#define DD 128
#define CLEN 16
#define NTOT 4096           // B*L
#define LISTCAP 512

// GEMM tiling (r10): 64x64 tile, 512 threads = 2 K-groups of 256.
// Each group = exact r0-proven structure (4x4 acc/thread, f32 LDS, 0-conflict
// layouts, in-loop cvt at optimal 0.5 cvt:FMA ratio) over half of K (BK=32,
// 8 iters). Combine halves with one deterministic f64 add via LDS.
// 8 waves/block x 3 blocks/CU = 24 waves/CU (r0 was 12, grid-limited).
#define RT6 64
#define CT6 64
#define BK6 32
// cpy tiling
#define CPB 16              // rows per cpy block

// output offsets (floats)
#define OFF_WORD  0
#define OFF_CHAR  4096
#define OFF_PSR   69632
#define OFF_ATK   593920
#define OFF_OBFM  1118208
#define OFF_CPYM  1122304
#define OFF_PRIM  1126400
#define OFF_CLOSS 1130496
#define OFF_ELOSS 1130497

// ws layout: floats [0..11]=ent partials [12]=closs ; ints [16..27]=cnt ;
// ints [64..6207]=rowlist ; floats [6656..14847]=scbuf ; floats [16384..]=logits
#define WS_SC_OFF     6656
#define WS_LOGITS_OFF 16384

// ---- CR-f32 transcendentals via double libm (bit-critical gate path) ----
__device__ __forceinline__ float EXP32(float x){ return (float)exp((double)x); }
__device__ __forceinline__ float LOG32(float x){ return (float)log((double)x); }

// ---- JAX threefry2x32 (20 rounds) — verified vs known-answer vector ----
__device__ __forceinline__ unsigned rotl32(unsigned x, int r){ return (x<<r)|(x>>(32-r)); }
__device__ __forceinline__ void tf2x32(unsigned k0, unsigned k1, unsigned x0, unsigned x1,
                                       unsigned &o0, unsigned &o1){
  unsigned ks2 = k0 ^ k1 ^ 0x1BD11BDAu;
  x0 += k0; x1 += k1;
  x0+=x1; x1=rotl32(x1,13); x1^=x0;
  x0+=x1; x1=rotl32(x1,15); x1^=x0;
  x0+=x1; x1=rotl32(x1,26); x1^=x0;
  x0+=x1; x1=rotl32(x1, 6); x1^=x0;
  x0+=k1; x1+=ks2+1u;
  x0+=x1; x1=rotl32(x1,17); x1^=x0;
  x0+=x1; x1=rotl32(x1,29); x1^=x0;
  x0+=x1; x1=rotl32(x1,16); x1^=x0;
  x0+=x1; x1=rotl32(x1,24); x1^=x0;
  x0+=ks2; x1+=k0+2u;
  x0+=x1; x1=rotl32(x1,13); x1^=x0;
  x0+=x1; x1=rotl32(x1,15); x1^=x0;
  x0+=x1; x1=rotl32(x1,26); x1^=x0;
  x0+=x1; x1=rotl32(x1, 6); x1^=x0;
  x0+=k0; x1+=k1+3u;
  x0+=x1; x1=rotl32(x1,17); x1^=x0;
  x0+=x1; x1=rotl32(x1,29); x1^=x0;
  x0+=x1; x1=rotl32(x1,16); x1^=x0;
  x0+=x1; x1=rotl32(x1,24); x1^=x0;
  x0+=k1; x1+=ks2+4u;
  x0+=x1; x1=rotl32(x1,13); x1^=x0;
  x0+=x1; x1=rotl32(x1,15); x1^=x0;
  x0+=x1; x1=rotl32(x1,26); x1^=x0;
  x0+=x1; x1=rotl32(x1, 6); x1^=x0;
  x0+=ks2; x1+=k0+5u;
  o0=x0; o1=x1;
}

// jax_threefry_partitionable=True random_bits: count (0,e), output o0^o1
__device__ __forceinline__ unsigned tf_bits32(unsigned k0, unsigned k1, unsigned e){
  unsigned o0, o1; tf2x32(k0, k1, 0u, e, o0, o1); return o0 ^ o1;
}

__device__ __forceinline__ float bits_to_unif(unsigned bits){
  const float lo = 1e-6f;
  const float hi = (float)(1.0 - 1e-6);
  const float span = hi - lo;
  unsigned fb = (bits >> 9) | 0x3f800000u;
  float f = __fsub_rn(__uint_as_float(fb), 1.0f);
  float r = __fadd_rn(__fmul_rn(f, span), lo);
  return fmaxf(lo, r);
}

// exact (CR) gumbel — cpy gate only (bit-critical: decides c in {1,1-2^-24})
__device__ __forceinline__ float gumbel_exact(unsigned bits){
  float u = bits_to_unif(bits);
  float v = -LOG32(u);
  return -LOG32(v);
}
// fast (ocml f32) gumbel — finalize argmax path (proven r5)
__device__ __forceinline__ float gumbel_fast(unsigned bits){
  float u = bits_to_unif(bits);
  float v = -logf(u);
  return -logf(v);
}

// ---- the copy-gate chain (CR double-libm path, bit-identical r2-r5) ----
__device__ __forceinline__ void gate_chain(int n, int pos, int msk,
                                           float p0f, float p1f,
                                           const float* __restrict__ cb2,
                                           float* __restrict__ sc0,
                                           float* __restrict__ sc1,
                                           float* __restrict__ closs)
{
  const bool ispri = (pos < 4);
  float pc0 = __fadd_rn(p0f, cb2[0]);
  float pc1 = __fadd_rn(p1f, cb2[1]);
  float m2  = fmaxf(pc0, pc1);
  float s0  = __fsub_rn(pc0, m2), s1 = __fsub_rn(pc1, m2);
  float se  = __fadd_rn(EXP32(s0), EXP32(s1));
  float lse = LOG32(se);
  float q0  = __fsub_rn(s0, lse), q1 = __fsub_rn(s1, lse);
  if (ispri){ q0 = 0.0f; q1 = 1.0f; }

  unsigned k90, k91; tf2x32(0u, 42u, 0u, 999u, k90, k91);
  float g0 = gumbel_exact(tf_bits32(k90, k91, (unsigned)(2*n)));
  float g1 = gumbel_exact(tf_bits32(k90, k91, (unsigned)(2*n + 1)));

  float x0 = __fadd_rn(q0, g0), x1 = __fadd_rn(q1, g1);
  float mmv = fmaxf(x0, x1);
  float ex0 = EXP32(__fsub_rn(x0, mmv));
  float ex1 = EXP32(__fsub_rn(x1, mmv));
  float ssum = __fadd_rn(ex0, ex1);
  float y0 = __fdiv_rn(ex0, ssum), y1 = __fdiv_rn(ex1, ssum);
  int   idx2 = (y1 > y0) ? 1 : 0;
  float ysel = idx2 ? y1 : y0;
  float c    = __fsub_rn(__fadd_rn(1.0f, ysel), ysel);
  *sc0 = (idx2 == 0) ? c : 0.0f;
  *sc1 = (idx2 == 1) ? c : 0.0f;

  float m3 = fmaxf(q0, q1);
  float t0 = __fsub_rn(q0, m3), t1 = __fsub_rn(q1, m3);
  float se2 = __fadd_rn(EXP32(t0), EXP32(t1));
  float l21 = __fsub_rn(t1, LOG32(se2));
  if (msk != 0 && (n & (LL-1)) != 0) atomicAdd(closs, l21);
}

// ---------- Kernel A: bucket build + tiled cpy MLP/gate (16 rows/block) ----------
__global__ __launch_bounds__(256)
void cpy_build_kernel(const float* __restrict__ ctx, const float* __restrict__ cW1,
                      const float* __restrict__ cb1, const float* __restrict__ cW2,
                      const float* __restrict__ cb2, const int* __restrict__ inp_pos,
                      const int* __restrict__ inp_mask, int* __restrict__ cntg,
                      int* __restrict__ rowlist, float* __restrict__ scbuf,
                      float* __restrict__ ws)
{
  const int n0 = blockIdx.x * CPB;
  const int t = threadIdx.x;

  if (t < CPB){
    int n = n0 + t;
    int p = inp_pos[n];
    if (p < PP){
      int slot = atomicAdd(&cntg[p], 1);
      if (slot < LISTCAP) rowlist[p*LISTCAP + slot] = n;
    }
  }

  __shared__ float W1s[64][68];     // [k][o], padded
  __shared__ float Cs[CPB][68];     // [row][k], padded

  const int r  = t >> 4;            // 0..15  (row)
  const int og = (t & 15) * 4;      // output group of 4
  double acc[4] = {0.0, 0.0, 0.0, 0.0};

  for (int k0 = 0; k0 < HSZ; k0 += 64){
    #pragma unroll
    for (int i = 0; i < 4; ++i){    // W1 chunk 64k x 64o
      int s = t + i*256;
      int kk = s >> 4, q = s & 15;
      float4 v = *(const float4*)(cW1 + (size_t)(k0+kk)*64 + q*4);
      *(float4*)&W1s[kk][q*4] = v;
    }
    {                               // ctx chunk 16 rows x 64 k
      int rr = t >> 4, q = t & 15;
      float4 v = *(const float4*)(ctx + (size_t)(n0+rr)*HSZ + k0 + q*4);
      *(float4*)&Cs[rr][q*4] = v;
    }
    __syncthreads();
    #pragma unroll 4
    for (int kk = 0; kk < 64; ++kk){
      double c = (double)Cs[r][kk];
      acc[0] += c * (double)W1s[kk][og+0];
      acc[1] += c * (double)W1s[kk][og+1];
      acc[2] += c * (double)W1s[kk][og+2];
      acc[3] += c * (double)W1s[kk][og+3];
    }
    __syncthreads();
  }

  // bias + relu + W2 partials, reduce across the 16 lanes of the row
  double p0 = 0.0, p1 = 0.0;
  #pragma unroll
  for (int j = 0; j < 4; ++j){
    float hv = __fadd_rn((float)acc[j], cb1[og+j]);
    hv = hv > 0.f ? hv : 0.f;
    double hd = (double)hv;
    p0 += hd * (double)cW2[2*(og+j)+0];
    p1 += hd * (double)cW2[2*(og+j)+1];
  }
  #pragma unroll
  for (int off = 1; off < 16; off <<= 1){
    p0 += __shfl_xor(p0, off);
    p1 += __shfl_xor(p1, off);
  }

  if ((t & 15) == 0){
    const int n = n0 + r;
    float c0v, c1v;
    gate_chain(n, inp_pos[n], inp_mask[n], (float)p0, (float)p1, cb2,
               &c0v, &c1v, ws + 12);
    scbuf[2*n + 0] = c0v;
    scbuf[2*n + 1] = c1v;
  }
}

// ---------- Kernel B: gathered GEMM 64x64, f64 acc, 2 K-groups ----------
// r10: 512 threads. Group g (256 threads) = r0-proven 4x4/thread structure
// over k in [g*256, g*256+256), BK=32. In-loop exact f32->f64 cvt (r0/r4
// numerics, 0-conflict layouts: As pitch 36 (==4 mod 32, same as proven 68),
// Bs pitch 68). Final logit = (sum over k<256) + (sum over k>=256): both
// chains bit-identical to r0's sub-chains; the single f64 add at the end
// differs from one long chain only at ~1e-15 rel — invisible after f32
// rounding (argmax-safe).
__global__ __launch_bounds__(512)
void gemm_kernel(const float* __restrict__ ctx, const float* __restrict__ dec_W,
                 const int* __restrict__ cntg, const int* __restrict__ rowlist,
                 float* __restrict__ logits)
{
  const int p  = blockIdx.z;
  const int c0 = blockIdx.x * CT6;
  const int r0 = blockIdx.y * RT6;
  const int cnt0 = cntg[p];
  const int cnt  = cnt0 < LISTCAP ? cnt0 : LISTCAP;
  if (r0 >= cnt) return;
  const int t = threadIdx.x;
  const int g  = t >> 8;            // k-group 0/1
  const int tl = t & 255;           // thread-in-group

  // pool: per-group As[64][36] (2304 f) + Bs[32][68] (2176 f) = 4480 f;
  // two groups = 8960 floats. Combine buffer overlays pool (4096 doubles).
  __shared__ double pool_d[4480];
  float* pool = (float*)pool_d;
  float* As = pool + g*4480;          // [64][36]
  float* Bs = pool + g*4480 + 2304;   // [32][68]
  double* comb = pool_d;              // [64][64] f64 after K loop
  __shared__ int rid_s[RT6];

  if (t < RT6){
    int rr = r0 + t;
    rid_s[t] = rowlist[p*LISTCAP + (rr < cnt ? rr : cnt-1)];
  }
  __syncthreads();

  const int tr = tl >> 4, tc = tl & 15;
  double acc[4][4];
  #pragma unroll
  for (int i = 0; i < 4; ++i)
    #pragma unroll
    for (int j = 0; j < 4; ++j) acc[i][j] = 0.0;

  const float* Wp = dec_W + (size_t)p * HSZ * MM;

  for (int it = 0; it < 8; ++it){
    const int kb = g*256 + it*BK6;
    #pragma unroll
    for (int i = 0; i < 2; ++i){    // A: 64 rows x 8 float4 (32 k)
      int s = tl + i*256;
      int rr = s >> 3, q = s & 7;
      float4 v = *(const float4*)(ctx + (size_t)rid_s[rr]*HSZ + kb + q*4);
      *(float4*)&As[rr*36 + q*4] = v;
    }
    #pragma unroll
    for (int i = 0; i < 2; ++i){    // B: 32 k x 16 float4 (64 c)
      int s = tl + i*256;
      int kk = s >> 4, q = s & 15;
      float4 v = *(const float4*)(Wp + (size_t)(kb+kk)*MM + c0 + q*4);
      *(float4*)&Bs[kk*68 + q*4] = v;
    }
    __syncthreads();
    #pragma unroll 4
    for (int kk = 0; kk < BK6; ++kk){
      float4 bf = *(const float4*)&Bs[kk*68 + tc*4];
      double b0=(double)bf.x, b1=(double)bf.y, b2=(double)bf.z, b3=(double)bf.w;
      double a0 = (double)As[(tr*4+0)*36 + kk];
      double a1 = (double)As[(tr*4+1)*36 + kk];
      double a2 = (double)As[(tr*4+2)*36 + kk];
      double a3 = (double)As[(tr*4+3)*36 + kk];
      acc[0][0]+=a0*b0; acc[0][1]+=a0*b1; acc[0][2]+=a0*b2; acc[0][3]+=a0*b3;
      acc[1][0]+=a1*b0; acc[1][1]+=a1*b1; acc[1][2]+=a1*b2; acc[1][3]+=a1*b3;
      acc[2][0]+=a2*b0; acc[2][1]+=a2*b1; acc[2][2]+=a2*b2; acc[2][3]+=a2*b3;
      acc[3][0]+=a3*b0; acc[3][1]+=a3*b1; acc[3][2]+=a3*b2; acc[3][3]+=a3*b3;
    }
    __syncthreads();
  }

  // combine: group1 deposits its half-sums; group0 adds (lo + hi) and writes
  if (g == 1){
    #pragma unroll
    for (int i = 0; i < 4; ++i)
      #pragma unroll
      for (int j = 0; j < 4; ++j)
        comb[(size_t)(tr*4+i)*64 + tc*4 + j] = acc[i][j];
  }
  __syncthreads();
  if (g == 0){
    #pragma unroll
    for (int i = 0; i < 4; ++i){
      int rr = r0 + tr*4 + i;
      if (rr < cnt){
        int rg = rid_s[tr*4 + i];
        float4 o;
        o.x = (float)(acc[i][0] + comb[(size_t)(tr*4+i)*64 + tc*4 + 0]);
        o.y = (float)(acc[i][1] + comb[(size_t)(tr*4+i)*64 + tc*4 + 1]);
        o.z = (float)(acc[i][2] + comb[(size_t)(tr*4+i)*64 + tc*4 + 2]);
        o.w = (float)(acc[i][3] + comb[(size_t)(tr*4+i)*64 + tc*4 + 3]);
        *(float4*)(logits + (size_t)rg*MM + c0 + tc*4) = o;
      }
    }
  }
}

// ---------- Kernel C: finalize, ONE WAVE PER ROW (no __syncthreads) ----------
__global__ __launch_bounds__(256)
void finalize_kernel(const float* __restrict__ dec_b,
                     const float* __restrict__ psr_w, const float* __restrict__ atk_w,
                     const int* __restrict__ inp_word, const int* __restrict__ inp_pos,
                     const int* __restrict__ inp_mask, const int* __restrict__ words,
                     const int* __restrict__ lut, const float* __restrict__ logitsbuf,
                     const float* __restrict__ scbuf,
                     float* __restrict__ out, float* __restrict__ ws)
{
  const int wid = threadIdx.x >> 6, lane = threadIdx.x & 63;
  const int n = blockIdx.x * 4 + wid;

  const int  pos   = inp_pos[n];
  const int  word  = inp_word[n];
  const int  msk   = inp_mask[n];
  const bool isobf = (pos < PP);
  const bool ispri = (pos < 4);
  const float c0 = scbuf[2*n + 0];
  const float c1 = scbuf[2*n + 1];

  int bi = 0;
  if (isobf){
    // load 16 logits per lane (coalesced float4 per iter), add bias
    float l[16];
    float lm = -3.4e38f;
    #pragma unroll
    for (int it = 0; it < 4; ++it){
      int m = it*256 + lane*4;
      float4 lg = *(const float4*)(logitsbuf + (size_t)n*MM + m);
      float4 bq = *(const float4*)(dec_b + (size_t)pos*MM + m);
      l[it*4+0] = __fadd_rn(lg.x, bq.x);
      l[it*4+1] = __fadd_rn(lg.y, bq.y);
      l[it*4+2] = __fadd_rn(lg.z, bq.z);
      l[it*4+3] = __fadd_rn(lg.w, bq.w);
      lm = fmaxf(lm, fmaxf(fmaxf(l[it*4+0], l[it*4+1]), fmaxf(l[it*4+2], l[it*4+3])));
    }
    #pragma unroll
    for (int off = 32; off > 0; off >>= 1) lm = fmaxf(lm, __shfl_xor(lm, off));
    const float xmax = lm;

    float e[16];
    double ds = 0.0;
    #pragma unroll
    for (int j = 0; j < 16; ++j){
      e[j] = expf(__fsub_rn(l[j], xmax));
      ds += (double)e[j];
    }
    #pragma unroll
    for (int off = 32; off > 0; off >>= 1) ds += __shfl_xor(ds, off);
    const double se = ds;
    const float lse = logf((float)se);
    const double inv_se = 1.0 / se;

    unsigned kp0, kp1; tf2x32(0u, 42u, 0u, (unsigned)pos, kp0, kp1);
    float best = -3.4e38f; double es = 0.0;
    #pragma unroll
    for (int it = 0; it < 4; ++it){
      #pragma unroll
      for (int j = 0; j < 4; ++j){
        int m = it*256 + lane*4 + j;
        float sh = __fsub_rn(l[it*4+j], xmax);
        float lp = __fsub_rn(sh, lse);
        es += (double)(-lp) * ((double)e[it*4+j] * inv_se);
        float g = gumbel_fast(tf_bits32(kp0, kp1, (unsigned)(n*MM + m)));
        float sv = __fadd_rn(lp, g);
        if (sv > best){ best = sv; bi = m; }
      }
    }
    #pragma unroll
    for (int off = 32; off > 0; off >>= 1){
      float ov = __shfl_xor(best, off);
      int   oi = __shfl_xor(bi,   off);
      if (ov > best || (ov == best && oi < bi)){ best = ov; bi = oi; }
      es += __shfl_xor(es, off);
    }
    if (lane == 0) atomicAdd(ws + pos, (float)es);
  }

  // ---------- epilogue (per wave = per row) ----------
  const int obf_word = isobf ? words[pos*MM + bi] : word;
  float of = __fadd_rn(__fmul_rn((float)word, c0), __fmul_rn((float)obf_word, c1));
  int ow = (int)of;
  if (lane == 0){
    out[OFF_WORD + n] = (float)ow;
    bool cpym = (c0 == 1.0f) && (msk != 0);
    out[OFF_CPYM + n] = cpym ? 1.f : 0.f;
    out[OFF_OBFM + n] = (isobf && !cpym) ? 1.f : 0.f;
    out[OFF_PRIM + n] = ispri ? 1.f : 0.f;
  }
  if (lane < CLEN)
    out[OFF_CHAR + (size_t)n*CLEN + lane] = (float)lut[(size_t)ow*CLEN + lane];
  #pragma unroll
  for (int rep = 0; rep < 2; ++rep){
    int j = lane + rep*64;
    float po = psr_w[(size_t)word*DD + j];
    float pb = isobf ? psr_w[(size_t)obf_word*DD + j] : po;
    out[OFF_PSR + (size_t)n*DD + j] = __fadd_rn(__fmul_rn(po, c0), __fmul_rn(pb, c1));
    float ao = atk_w[(size_t)word*DD + j];
    float ab = isobf ? atk_w[(size_t)obf_word*DD + j] : ao;
    out[OFF_ATK + (size_t)n*DD + j] = __fadd_rn(__fmul_rn(ao, c0), __fmul_rn(ab, c1));
  }
}

// ---------- losses ----------
__global__ __launch_bounds__(256)
void fin_kernel(const int* __restrict__ inp_pos, const int* __restrict__ inp_mask,
                const float* __restrict__ ws, float* __restrict__ out)
{
  __shared__ int cnt[PP];
  __shared__ int nr;
  int t = threadIdx.x;
  if (t < PP) cnt[t] = 0;
  if (t == 0) nr = 0;
  __syncthreads();
  int ln = 0;
  for (int n = t; n < NTOT; n += 256){
    int p = inp_pos[n];
    if (p < PP) atomicAdd(&cnt[p], 1);
    if (inp_mask[n] != 0 && (n & (LL-1)) != 0) ln++;
  }
  atomicAdd(&nr, ln);
  __syncthreads();
  if (t == 0){
    float ent = 0.f;
    for (int p = 0; p < PP; ++p){
      int c = cnt[p];
      if (c > 0){
        int denom = c * MM; if (denom < 1) denom = 1;
        ent = __fadd_rn(ent, __fdiv_rn(ws[p], (float)denom));
      }
    }
    out[OFF_ELOSS] = -ent;
    int nrc = nr; if (nrc < 1) nrc = 1;
    out[OFF_CLOSS] = -__fdiv_rn(ws[12], (float)nrc);
  }
}

// ---------- monolithic fallback (r2, proven) for tiny ws ----------
__global__ __launch_bounds__(256)
void row_kernel_mono(const float* __restrict__ ctx, const float* __restrict__ dec_W,
                const float* __restrict__ dec_b, const float* __restrict__ psr_w,
                const float* __restrict__ atk_w, const float* __restrict__ cW1,
                const float* __restrict__ cb1, const float* __restrict__ cW2,
                const float* __restrict__ cb2, const int* __restrict__ inp_word,
                const int* __restrict__ inp_pos, const int* __restrict__ inp_mask,
                const int* __restrict__ words, const int* __restrict__ lut,
                float* __restrict__ out, float* __restrict__ ws)
{
  const int n = blockIdx.x;
  const int t = threadIdx.x;

  __shared__ float  ctx_s[HSZ];
  __shared__ float  logit_s[MM];
  __shared__ float  h_s[64];
  __shared__ double redd[256];
  __shared__ float  redf[256];
  __shared__ int    redi[256];
  __shared__ float  sc[2];
  __shared__ int    si[1];

  for (int k = t; k < HSZ; k += 256) ctx_s[k] = ctx[(size_t)n*HSZ + k];
  __syncthreads();

  const int  pos   = inp_pos[n];
  const int  word  = inp_word[n];
  const int  msk   = inp_mask[n];
  const bool isobf = (pos < PP);
  const bool ispri = (pos < 4);

  if (t < 64){
    double acc = 0.0;
    for (int k = 0; k < HSZ; ++k) acc += (double)ctx_s[k] * (double)cW1[k*64 + t];
    float hv = __fadd_rn((float)acc, cb1[t]);
    h_s[t] = hv > 0.f ? hv : 0.f;
  }
  __syncthreads();

  if (t == 0){
    double a0 = 0.0, a1 = 0.0;
    for (int k = 0; k < 64; ++k){
      double hv = (double)h_s[k];
      a0 += hv * (double)cW2[k*2 + 0];
      a1 += hv * (double)cW2[k*2 + 1];
    }
    float c0v, c1v;
    gate_chain(n, pos, msk, (float)a0, (float)a1, cb2, &c0v, &c1v, ws + 12);
    sc[0] = c0v; sc[1] = c1v;
  }

  if (isobf){
    const float4* W4 = (const float4*)(dec_W + (size_t)pos * HSZ * MM);
    double a0=0.0, a1=0.0, a2=0.0, a3=0.0;
    for (int k = 0; k < HSZ; ++k){
      double c = (double)ctx_s[k];
      float4 w = W4[(size_t)k*256 + t];
      a0 += c*(double)w.x; a1 += c*(double)w.y; a2 += c*(double)w.z; a3 += c*(double)w.w;
    }
    const float* bp = dec_b + (size_t)pos * MM;
    const int m0 = 4*t;
    logit_s[m0+0] = __fadd_rn((float)a0, bp[m0+0]);
    logit_s[m0+1] = __fadd_rn((float)a1, bp[m0+1]);
    logit_s[m0+2] = __fadd_rn((float)a2, bp[m0+2]);
    logit_s[m0+3] = __fadd_rn((float)a3, bp[m0+3]);
    __syncthreads();

    float lm = logit_s[m0];
    lm = fmaxf(lm, logit_s[m0+1]); lm = fmaxf(lm, logit_s[m0+2]); lm = fmaxf(lm, logit_s[m0+3]);
    redf[t] = lm; __syncthreads();
    for (int s = 128; s > 0; s >>= 1){ if (t < s) redf[t] = fmaxf(redf[t], redf[t+s]); __syncthreads(); }
    const float xmax = redf[0];
    __syncthreads();

    double dsm = 0.0;
    for (int j = 0; j < 4; ++j)
      dsm += (double)EXP32(__fsub_rn(logit_s[m0+j], xmax));
    redd[t] = dsm; __syncthreads();
    for (int s = 128; s > 0; s >>= 1){ if (t < s) redd[t] += redd[t+s]; __syncthreads(); }
    const float lse = LOG32((float)redd[0]);
    __syncthreads();

    unsigned kp0, kp1; tf2x32(0u, 42u, 0u, (unsigned)pos, kp0, kp1);
    float best = -3.4e38f; int bi = 0; double es = 0.0;
    for (int j = 0; j < 4; ++j){
      int m = m0 + j;
      float sh = __fsub_rn(logit_s[m], xmax);
      float lp = __fsub_rn(sh, lse);
      float ex = EXP32(lp);
      es += (double)__fmul_rn(-lp, ex);
      float g = gumbel_exact(tf_bits32(kp0, kp1, (unsigned)(n*MM + m)));
      float sv = __fadd_rn(lp, g);
      if (sv > best){ best = sv; bi = m; }
    }
    redf[t] = best; redi[t] = bi; redd[t] = es; __syncthreads();
    for (int s = 128; s > 0; s >>= 1){
      if (t < s){
        float v2 = redf[t+s]; int i2 = redi[t+s];
        if (v2 > redf[t] || (v2 == redf[t] && i2 < redi[t])){ redf[t] = v2; redi[t] = i2; }
        redd[t] += redd[t+s];
      }
      __syncthreads();
    }
    if (t == 0){ si[0] = redi[0]; atomicAdd(ws + pos, (float)redd[0]); }
    __syncthreads();
  } else {
    __syncthreads();
  }

  const int   idx = isobf ? si[0] : 0;
  const float c0 = sc[0], c1 = sc[1];
  const int   obf_word = isobf ? words[pos*MM + idx] : word;

  if (t == 0){
    float of = __fadd_rn(__fmul_rn((float)word, c0), __fmul_rn((float)obf_word, c1));
    int ow = (int)of;
    out[OFF_WORD + n] = (float)ow;
    bool cpym = (c0 == 1.0f) && (msk != 0);
    out[OFF_CPYM + n] = cpym ? 1.f : 0.f;
    out[OFF_OBFM + n] = (isobf && !cpym) ? 1.f : 0.f;
    out[OFF_PRIM + n] = ispri ? 1.f : 0.f;
    #pragma unroll
    for (int j = 0; j < CLEN; ++j)
      out[OFF_CHAR + (size_t)n*CLEN + j] = (float)lut[(size_t)ow*CLEN + j];
  }
  if (t < DD){
    float po = psr_w[(size_t)word*DD + t];
    float pb = isobf ? psr_w[(size_t)obf_word*DD + t] : po;
    out[OFF_PSR + (size_t)n*DD + t] = __fadd_rn(__fmul_rn(po, c0), __fmul_rn(pb, c1));
    float ao = atk_w[(size_t)word*DD + t];
    float ab = isobf ? atk_w[(size_t)obf_word*DD + t] : ao;
    out[OFF_ATK + (size_t)n*DD + t] = __fadd_rn(__fmul_rn(ao, c0), __fmul_rn(ab, c1));
  }
}

extern "C" void kernel_launch(void* const* d_in, const int* in_sizes, int n_in,
                              void* d_out, int out_size, void* d_ws, size_t ws_size,
                              hipStream_t stream)
{
  const float* ctx      = (const float*)d_in[0];
  const float* dec_W    = (const float*)d_in[1];
  const float* dec_b    = (const float*)d_in[2];
  const float* psr_w    = (const float*)d_in[3];
  const float* atk_w    = (const float*)d_in[4];
  const float* cW1      = (const float*)d_in[5];
  const float* cb1      = (const float*)d_in[6];
  const float* cW2      = (const float*)d_in[7];
  const float* cb2      = (const float*)d_in[8];
  const int*   inp_word = (const int*)d_in[9];
  const int*   inp_pos  = (const int*)d_in[10];
  const int*   inp_mask = (const int*)d_in[11];
  const int*   words    = (const int*)d_in[12];
  const int*   lut      = (const int*)d_in[13];
  float* out = (float*)d_out;
  float* ws  = (float*)d_ws;

  const size_t need = ((size_t)WS_LOGITS_OFF + (size_t)NTOT*MM) * 4;

  hipMemsetAsync(ws, 0, 512, stream);   // ent/closs floats + cnt ints

  if (ws_size >= need){
    int*   cntg      = (int*)ws + 16;
    int*   rowlist   = (int*)ws + 64;
    float* scbuf     = ws + WS_SC_OFF;
    float* logitsbuf = ws + WS_LOGITS_OFF;
    cpy_build_kernel<<<NTOT/CPB, 256, 0, stream>>>(ctx, cW1, cb1, cW2, cb2,
                                                   inp_pos, inp_mask, cntg, rowlist,
                                                   scbuf, ws);
    gemm_kernel<<<dim3(MM/CT6, LISTCAP/RT6, PP), 512, 0, stream>>>(ctx, dec_W, cntg,
                                                                   rowlist, logitsbuf);
    finalize_kernel<<<NTOT/4, 256, 0, stream>>>(dec_b, psr_w, atk_w,
                                                inp_word, inp_pos, inp_mask, words, lut,
                                                logitsbuf, scbuf, out, ws);
  } else {
    row_kernel_mono<<<NTOT, 256, 0, stream>>>(ctx, dec_W, dec_b, psr_w, atk_w,
                                              cW1, cb1, cW2, cb2,
                                              inp_word, inp_pos, inp_mask, words, lut,
                                              out, ws);
  }
  fin_kernel<<<1, 256, 0, stream>>>(inp_pos, inp_mask, ws, out);
}

// Round 7
// 322.614 us; speedup vs baseline: 1.1606x; 1.0383x over previous
//
#include <hip/hip_runtime.h>
#include <math.h>

// ---- problem constants ----
#define BB 32
#define LL 128
#define HSZ 512
#define PP 12
#define MM 1024
#define VV 50000
#define DD 128
#define CLEN 16
#define NTOT 4096           // B*L
#define LISTCAP 512

// GEMM tiling (r2-proven best: 119.7us): 64x64, BK2=32, f64 LDS staging.
#define RT 64
#define CT 64
#define BK2 32
// cpy tiling
#define CPB 16              // rows per cpy block

// output offsets (floats)
#define OFF_WORD  0
#define OFF_CHAR  4096
#define OFF_PSR   69632
#define OFF_ATK   593920
#define OFF_OBFM  1118208
#define OFF_CPYM  1122304
#define OFF_PRIM  1126400
#define OFF_CLOSS 1130496
#define OFF_ELOSS 1130497

// ws layout (unchanged footprint): floats [0..15] legacy scalars ; ints
// [16..27]=cnt ; ints [64..6207]=rowlist ; floats [6656..14847]=scbuf
// (scbuf[2n]=sign-packed gate, scbuf[2n+1]=l21) ; floats [16384..]=logits.
// Per-row entropy is stashed in logitsbuf[n*MM] by finalize (row already
// consumed), so no extra ws space is needed.
#define WS_SC_OFF     6656
#define WS_LOGITS_OFF 16384

// ---- CR-f32 transcendentals via double libm (bit-critical gate path) ----
__device__ __forceinline__ float EXP32(float x){ return (float)exp((double)x); }
__device__ __forceinline__ float LOG32(float x){ return (float)log((double)x); }

// ---- JAX threefry2x32 (20 rounds) — verified vs known-answer vector ----
__device__ __forceinline__ unsigned rotl32(unsigned x, int r){ return (x<<r)|(x>>(32-r)); }
__device__ __forceinline__ void tf2x32(unsigned k0, unsigned k1, unsigned x0, unsigned x1,
                                       unsigned &o0, unsigned &o1){
  unsigned ks2 = k0 ^ k1 ^ 0x1BD11BDAu;
  x0 += k0; x1 += k1;
  x0+=x1; x1=rotl32(x1,13); x1^=x0;
  x0+=x1; x1=rotl32(x1,15); x1^=x0;
  x0+=x1; x1=rotl32(x1,26); x1^=x0;
  x0+=x1; x1=rotl32(x1, 6); x1^=x0;
  x0+=k1; x1+=ks2+1u;
  x0+=x1; x1=rotl32(x1,17); x1^=x0;
  x0+=x1; x1=rotl32(x1,29); x1^=x0;
  x0+=x1; x1=rotl32(x1,16); x1^=x0;
  x0+=x1; x1=rotl32(x1,24); x1^=x0;
  x0+=ks2; x1+=k0+2u;
  x0+=x1; x1=rotl32(x1,13); x1^=x0;
  x0+=x1; x1=rotl32(x1,15); x1^=x0;
  x0+=x1; x1=rotl32(x1,26); x1^=x0;
  x0+=x1; x1=rotl32(x1, 6); x1^=x0;
  x0+=k0; x1+=k1+3u;
  x0+=x1; x1=rotl32(x1,17); x1^=x0;
  x0+=x1; x1=rotl32(x1,29); x1^=x0;
  x0+=x1; x1=rotl32(x1,16); x1^=x0;
  x0+=x1; x1=rotl32(x1,24); x1^=x0;
  x0+=k1; x1+=ks2+4u;
  x0+=x1; x1=rotl32(x1,13); x1^=x0;
  x0+=x1; x1=rotl32(x1,15); x1^=x0;
  x0+=x1; x1=rotl32(x1,26); x1^=x0;
  x0+=x1; x1=rotl32(x1, 6); x1^=x0;
  x0+=ks2; x1+=k0+5u;
  o0=x0; o1=x1;
}

// jax_threefry_partitionable=True random_bits: count (0,e), output o0^o1
__device__ __forceinline__ unsigned tf_bits32(unsigned k0, unsigned k1, unsigned e){
  unsigned o0, o1; tf2x32(k0, k1, 0u, e, o0, o1); return o0 ^ o1;
}

__device__ __forceinline__ float bits_to_unif(unsigned bits){
  const float lo = 1e-6f;
  const float hi = (float)(1.0 - 1e-6);
  const float span = hi - lo;
  unsigned fb = (bits >> 9) | 0x3f800000u;
  float f = __fsub_rn(__uint_as_float(fb), 1.0f);
  float r = __fadd_rn(__fmul_rn(f, span), lo);
  return fmaxf(lo, r);
}

// exact (CR) gumbel — cpy gate only (bit-critical: decides c in {1,1-2^-24})
__device__ __forceinline__ float gumbel_exact(unsigned bits){
  float u = bits_to_unif(bits);
  float v = -LOG32(u);
  return -LOG32(v);
}
// fast (ocml f32) gumbel — finalize argmax path (proven r5)
__device__ __forceinline__ float gumbel_fast(unsigned bits){
  float u = bits_to_unif(bits);
  float v = -logf(u);
  return -logf(v);
}

// ---- the copy-gate chain (CR double-libm path, bit-identical math) ----
// Now returns sign-packed gate (s<0 -> c0=-s,c1=0 ; s>0 -> c0=0,c1=s) and
// raw l21 (mask condition applied by the reducer).
__device__ __forceinline__ void gate_chain(int n, int pos,
                                           float p0f, float p1f,
                                           const float* __restrict__ cb2,
                                           float* __restrict__ sc_enc,
                                           float* __restrict__ l21_out)
{
  const bool ispri = (pos < 4);
  float pc0 = __fadd_rn(p0f, cb2[0]);
  float pc1 = __fadd_rn(p1f, cb2[1]);
  float m2  = fmaxf(pc0, pc1);
  float s0  = __fsub_rn(pc0, m2), s1 = __fsub_rn(pc1, m2);
  float se  = __fadd_rn(EXP32(s0), EXP32(s1));
  float lse = LOG32(se);
  float q0  = __fsub_rn(s0, lse), q1 = __fsub_rn(s1, lse);
  if (ispri){ q0 = 0.0f; q1 = 1.0f; }

  unsigned k90, k91; tf2x32(0u, 42u, 0u, 999u, k90, k91);
  float g0 = gumbel_exact(tf_bits32(k90, k91, (unsigned)(2*n)));
  float g1 = gumbel_exact(tf_bits32(k90, k91, (unsigned)(2*n + 1)));

  float x0 = __fadd_rn(q0, g0), x1 = __fadd_rn(q1, g1);
  float mmv = fmaxf(x0, x1);
  float ex0 = EXP32(__fsub_rn(x0, mmv));
  float ex1 = EXP32(__fsub_rn(x1, mmv));
  float ssum = __fadd_rn(ex0, ex1);
  float y0 = __fdiv_rn(ex0, ssum), y1 = __fdiv_rn(ex1, ssum);
  int   idx2 = (y1 > y0) ? 1 : 0;
  float ysel = idx2 ? y1 : y0;
  float c    = __fsub_rn(__fadd_rn(1.0f, ysel), ysel);
  *sc_enc = idx2 ? c : -c;

  float m3 = fmaxf(q0, q1);
  float t0 = __fsub_rn(q0, m3), t1 = __fsub_rn(q1, m3);
  float se2 = __fadd_rn(EXP32(t0), EXP32(t1));
  *l21_out = __fsub_rn(t1, LOG32(se2));
}

// ---------- Kernel 0: ordered bucket build, ZERO atomics ----------
// Block p compacts rows with pos==p in ascending n via ballot-scan.
__global__ __launch_bounds__(256)
void bucket_kernel(const int* __restrict__ inp_pos, int* __restrict__ cntg,
                   int* __restrict__ rowlist)
{
  const int p = blockIdx.x;
  const int t = threadIdx.x;
  const int w = t >> 6, lane = t & 63;
  __shared__ int wtot[4];
  __shared__ int base_s;
  if (t == 0) base_s = 0;
  __syncthreads();
  for (int n0 = 0; n0 < NTOT; n0 += 256){
    int n = n0 + t;
    int m = (inp_pos[n] == p) ? 1 : 0;
    unsigned long long bal = __ballot(m);
    int excl = __popcll(bal & ((1ULL << lane) - 1ULL));
    if (lane == 0) wtot[w] = __popcll(bal);
    __syncthreads();
    int wbase = 0;
    #pragma unroll
    for (int i = 0; i < 4; ++i) if (i < w) wbase += wtot[i];
    int tot = wtot[0] + wtot[1] + wtot[2] + wtot[3];
    int b = base_s;
    if (m){
      int slot = b + wbase + excl;
      if (slot < LISTCAP) rowlist[p*LISTCAP + slot] = n;
    }
    __syncthreads();
    if (t == 0) base_s = b + tot;
    __syncthreads();
  }
  if (t == 0) cntg[p] = base_s;
}

// ---------- Kernel A: tiled cpy MLP/gate (16 rows/block), no atomics ----------
__global__ __launch_bounds__(256)
void cpy_build_kernel(const float* __restrict__ ctx, const float* __restrict__ cW1,
                      const float* __restrict__ cb1, const float* __restrict__ cW2,
                      const float* __restrict__ cb2, const int* __restrict__ inp_pos,
                      float* __restrict__ scbuf)
{
  const int n0 = blockIdx.x * CPB;
  const int t = threadIdx.x;

  __shared__ float W1s[64][68];     // [k][o], padded
  __shared__ float Cs[CPB][68];     // [row][k], padded

  const int r  = t >> 4;            // 0..15  (row)
  const int og = (t & 15) * 4;      // output group of 4
  double acc[4] = {0.0, 0.0, 0.0, 0.0};

  for (int k0 = 0; k0 < HSZ; k0 += 64){
    #pragma unroll
    for (int i = 0; i < 4; ++i){    // W1 chunk 64k x 64o
      int s = t + i*256;
      int kk = s >> 4, q = s & 15;
      float4 v = *(const float4*)(cW1 + (size_t)(k0+kk)*64 + q*4);
      *(float4*)&W1s[kk][q*4] = v;
    }
    {                               // ctx chunk 16 rows x 64 k
      int rr = t >> 4, q = t & 15;
      float4 v = *(const float4*)(ctx + (size_t)(n0+rr)*HSZ + k0 + q*4);
      *(float4*)&Cs[rr][q*4] = v;
    }
    __syncthreads();
    #pragma unroll 4
    for (int kk = 0; kk < 64; ++kk){
      double c = (double)Cs[r][kk];
      acc[0] += c * (double)W1s[kk][og+0];
      acc[1] += c * (double)W1s[kk][og+1];
      acc[2] += c * (double)W1s[kk][og+2];
      acc[3] += c * (double)W1s[kk][og+3];
    }
    __syncthreads();
  }

  // bias + relu + W2 partials, reduce across the 16 lanes of the row
  double p0 = 0.0, p1 = 0.0;
  #pragma unroll
  for (int j = 0; j < 4; ++j){
    float hv = __fadd_rn((float)acc[j], cb1[og+j]);
    hv = hv > 0.f ? hv : 0.f;
    double hd = (double)hv;
    p0 += hd * (double)cW2[2*(og+j)+0];
    p1 += hd * (double)cW2[2*(og+j)+1];
  }
  #pragma unroll
  for (int off = 1; off < 16; off <<= 1){
    p0 += __shfl_xor(p0, off);
    p1 += __shfl_xor(p1, off);
  }

  if ((t & 15) == 0){
    const int n = n0 + r;
    float senc, l21;
    gate_chain(n, inp_pos[n], (float)p0, (float)p1, cb2, &senc, &l21);
    scbuf[2*n + 0] = senc;
    scbuf[2*n + 1] = l21;
  }
}

// ---------- Kernel B: gathered GEMM 64x64, f64 acc (r2-proven, 119.7us) ----------
__global__ __launch_bounds__(256)
void gemm_kernel(const float* __restrict__ ctx, const float* __restrict__ dec_W,
                 const int* __restrict__ cntg, const int* __restrict__ rowlist,
                 float* __restrict__ logits)
{
  const int p  = blockIdx.z;
  const int c0 = blockIdx.x * CT;
  const int r0 = blockIdx.y * RT;
  const int cnt0 = cntg[p];
  const int cnt  = cnt0 < LISTCAP ? cnt0 : LISTCAP;
  if (r0 >= cnt) return;
  const int t = threadIdx.x;

  __shared__ double As[RT][BK2+2];     // pitch 34 doubles: a-reads 2-way (free)
  __shared__ double Bs[BK2][16][6];    // sub-blocked: b128 reads 2-way (free)
  __shared__ int    rid_s[RT];

  if (t < RT){
    int rr = r0 + t;
    rid_s[t] = rowlist[p*LISTCAP + (rr < cnt ? rr : cnt-1)];
  }
  __syncthreads();

  const int tr = t >> 4, tc = t & 15;
  double acc[4][4];
  #pragma unroll
  for (int i = 0; i < 4; ++i)
    #pragma unroll
    for (int j = 0; j < 4; ++j) acc[i][j] = 0.0;

  const float* Wp = dec_W + (size_t)p * HSZ * MM;

  for (int k0 = 0; k0 < HSZ; k0 += BK2){
    // stage A: 64 rows x 32 k  (512 float4s, 2/thread), convert to f64
    #pragma unroll
    for (int i = 0; i < 2; ++i){
      int s = t + i*256;
      int rr = s >> 3, q = s & 7;       // row, k-group (k = q*4)
      float4 v = *(const float4*)(ctx + (size_t)rid_s[rr]*HSZ + k0 + q*4);
      double2 d0; d0.x = (double)v.x; d0.y = (double)v.y;
      double2 d1; d1.x = (double)v.z; d1.y = (double)v.w;
      *(double2*)&As[rr][q*4 + 0] = d0;   // (rr*34 + q*4) even -> 16B aligned
      *(double2*)&As[rr][q*4 + 2] = d1;
    }
    // stage B: 32 k x 64 c  (512 float4s, 2/thread), convert to f64
    #pragma unroll
    for (int i = 0; i < 2; ++i){
      int s = t + i*256;
      int kk = s >> 4, q = s & 15;      // k, col-group (col = q*4)
      float4 v = *(const float4*)(Wp + (size_t)(k0+kk)*MM + c0 + q*4);
      double2 d0; d0.x = (double)v.x; d0.y = (double)v.y;
      double2 d1; d1.x = (double)v.z; d1.y = (double)v.w;
      *(double2*)&Bs[kk][q][0] = d0;      // pitch 6 doubles -> 16B aligned
      *(double2*)&Bs[kk][q][2] = d1;
    }
    __syncthreads();
    #pragma unroll 4
    for (int kk = 0; kk < BK2; ++kk){
      double b0 = Bs[kk][tc][0];
      double b1 = Bs[kk][tc][1];
      double b2 = Bs[kk][tc][2];
      double b3 = Bs[kk][tc][3];
      double a0 = As[tr*4+0][kk];
      double a1 = As[tr*4+1][kk];
      double a2 = As[tr*4+2][kk];
      double a3 = As[tr*4+3][kk];
      acc[0][0]+=a0*b0; acc[0][1]+=a0*b1; acc[0][2]+=a0*b2; acc[0][3]+=a0*b3;
      acc[1][0]+=a1*b0; acc[1][1]+=a1*b1; acc[1][2]+=a1*b2; acc[1][3]+=a1*b3;
      acc[2][0]+=a2*b0; acc[2][1]+=a2*b1; acc[2][2]+=a2*b2; acc[2][3]+=a2*b3;
      acc[3][0]+=a3*b0; acc[3][1]+=a3*b1; acc[3][2]+=a3*b2; acc[3][3]+=a3*b3;
    }
    __syncthreads();
  }

  #pragma unroll
  for (int i = 0; i < 4; ++i){
    int rr = r0 + tr*4 + i;
    if (rr < cnt){
      int rg = rid_s[tr*4 + i];
      float4 o;
      o.x=(float)acc[i][0]; o.y=(float)acc[i][1]; o.z=(float)acc[i][2]; o.w=(float)acc[i][3];
      *(float4*)(logits + (size_t)rg*MM + c0 + tc*4) = o;
    }
  }
}

// ---------- Kernel C: finalize, ONE WAVE PER ROW, no atomics ----------
// Per-row entropy es is stashed into logitsbuf[n*MM] (row already consumed).
__global__ __launch_bounds__(256)
void finalize_kernel(const float* __restrict__ dec_b,
                     const float* __restrict__ psr_w, const float* __restrict__ atk_w,
                     const int* __restrict__ inp_word, const int* __restrict__ inp_pos,
                     const int* __restrict__ inp_mask, const int* __restrict__ words,
                     const int* __restrict__ lut, float* __restrict__ logitsbuf,
                     const float* __restrict__ scbuf,
                     float* __restrict__ out)
{
  const int wid = threadIdx.x >> 6, lane = threadIdx.x & 63;
  const int n = blockIdx.x * 4 + wid;

  const int  pos   = inp_pos[n];
  const int  word  = inp_word[n];
  const int  msk   = inp_mask[n];
  const bool isobf = (pos < PP);
  const bool ispri = (pos < 4);
  const float senc = scbuf[2*n + 0];
  const float c0 = (senc < 0.f) ? -senc : 0.f;
  const float c1 = (senc < 0.f) ? 0.f : senc;

  int bi = 0;
  if (isobf){
    // load 16 logits per lane (coalesced float4 per iter), add bias
    float l[16];
    float lm = -3.4e38f;
    #pragma unroll
    for (int it = 0; it < 4; ++it){
      int m = it*256 + lane*4;
      float4 lg = *(const float4*)(logitsbuf + (size_t)n*MM + m);
      float4 bq = *(const float4*)(dec_b + (size_t)pos*MM + m);
      l[it*4+0] = __fadd_rn(lg.x, bq.x);
      l[it*4+1] = __fadd_rn(lg.y, bq.y);
      l[it*4+2] = __fadd_rn(lg.z, bq.z);
      l[it*4+3] = __fadd_rn(lg.w, bq.w);
      lm = fmaxf(lm, fmaxf(fmaxf(l[it*4+0], l[it*4+1]), fmaxf(l[it*4+2], l[it*4+3])));
    }
    #pragma unroll
    for (int off = 32; off > 0; off >>= 1) lm = fmaxf(lm, __shfl_xor(lm, off));
    const float xmax = lm;

    float e[16];
    double ds = 0.0;
    #pragma unroll
    for (int j = 0; j < 16; ++j){
      e[j] = expf(__fsub_rn(l[j], xmax));
      ds += (double)e[j];
    }
    #pragma unroll
    for (int off = 32; off > 0; off >>= 1) ds += __shfl_xor(ds, off);
    const double se = ds;
    const float lse = logf((float)se);
    const double inv_se = 1.0 / se;

    unsigned kp0, kp1; tf2x32(0u, 42u, 0u, (unsigned)pos, kp0, kp1);
    float best = -3.4e38f; double es = 0.0;
    #pragma unroll
    for (int it = 0; it < 4; ++it){
      #pragma unroll
      for (int j = 0; j < 4; ++j){
        int m = it*256 + lane*4 + j;
        float sh = __fsub_rn(l[it*4+j], xmax);
        float lp = __fsub_rn(sh, lse);
        es += (double)(-lp) * ((double)e[it*4+j] * inv_se);
        float g = gumbel_fast(tf_bits32(kp0, kp1, (unsigned)(n*MM + m)));
        float sv = __fadd_rn(lp, g);
        if (sv > best){ best = sv; bi = m; }
      }
    }
    #pragma unroll
    for (int off = 32; off > 0; off >>= 1){
      float ov = __shfl_xor(best, off);
      int   oi = __shfl_xor(bi,   off);
      if (ov > best || (ov == best && oi < bi)){ best = ov; bi = oi; }
      es += __shfl_xor(es, off);
    }
    if (lane == 0) logitsbuf[(size_t)n*MM] = (float)es;
  } else {
    if (lane == 0) logitsbuf[(size_t)n*MM] = 0.f;
  }

  // ---------- epilogue (per wave = per row) ----------
  const int obf_word = isobf ? words[pos*MM + bi] : word;
  float of = __fadd_rn(__fmul_rn((float)word, c0), __fmul_rn((float)obf_word, c1));
  int ow = (int)of;
  if (lane == 0){
    out[OFF_WORD + n] = (float)ow;
    bool cpym = (c0 == 1.0f) && (msk != 0);
    out[OFF_CPYM + n] = cpym ? 1.f : 0.f;
    out[OFF_OBFM + n] = (isobf && !cpym) ? 1.f : 0.f;
    out[OFF_PRIM + n] = ispri ? 1.f : 0.f;
  }
  if (lane < CLEN)
    out[OFF_CHAR + (size_t)n*CLEN + lane] = (float)lut[(size_t)ow*CLEN + lane];
  #pragma unroll
  for (int rep = 0; rep < 2; ++rep){
    int j = lane + rep*64;
    float po = psr_w[(size_t)word*DD + j];
    float pb = isobf ? psr_w[(size_t)obf_word*DD + j] : po;
    out[OFF_PSR + (size_t)n*DD + j] = __fadd_rn(__fmul_rn(po, c0), __fmul_rn(pb, c1));
    float ao = atk_w[(size_t)word*DD + j];
    float ab = isobf ? atk_w[(size_t)obf_word*DD + j] : ao;
    out[OFF_ATK + (size_t)n*DD + j] = __fadd_rn(__fmul_rn(ao, c0), __fmul_rn(ab, c1));
  }
}

// ---------- losses: one wave per p, ordered f64 reductions, no atomics ----------
__global__ __launch_bounds__(1024)
void fin2_kernel(const int* __restrict__ inp_pos, const int* __restrict__ inp_mask,
                 const float* __restrict__ scbuf, const float* __restrict__ logitsbuf,
                 float* __restrict__ out)
{
  const int t = threadIdx.x;
  const int w = t >> 6, lane = t & 63;
  __shared__ double s_ent[PP];
  __shared__ int    s_cnt[PP];
  __shared__ double s_cl;
  __shared__ int    s_nr;

  if (w < PP){
    const int p = w;
    double es = 0.0; int c = 0;
    for (int n = lane; n < NTOT; n += 64){
      if (inp_pos[n] == p){
        es += (double)logitsbuf[(size_t)n*MM];
        c  += 1;
      }
    }
    #pragma unroll
    for (int off = 1; off < 64; off <<= 1){
      es += __shfl_xor(es, off);
      c  += __shfl_xor(c, off);
    }
    if (lane == 0){ s_ent[p] = es; s_cnt[p] = c; }
  } else if (w == PP){
    double cl = 0.0; int nr = 0;
    for (int n = lane; n < NTOT; n += 64){
      if (inp_mask[n] != 0 && (n & (LL-1)) != 0){
        cl += (double)scbuf[2*n + 1];
        nr += 1;
      }
    }
    #pragma unroll
    for (int off = 1; off < 64; off <<= 1){
      cl += __shfl_xor(cl, off);
      nr += __shfl_xor(nr, off);
    }
    if (lane == 0){ s_cl = cl; s_nr = nr; }
  }
  __syncthreads();
  if (t == 0){
    float ent = 0.f;
    for (int p = 0; p < PP; ++p){
      int c = s_cnt[p];
      if (c > 0){
        int denom = c * MM; if (denom < 1) denom = 1;
        ent = __fadd_rn(ent, __fdiv_rn((float)s_ent[p], (float)denom));
      }
    }
    out[OFF_ELOSS] = -ent;
    int nrc = s_nr; if (nrc < 1) nrc = 1;
    out[OFF_CLOSS] = -__fdiv_rn((float)s_cl, (float)nrc);
  }
}

// ---------- legacy losses kernel (fallback path only) ----------
__global__ __launch_bounds__(256)
void fin_kernel(const int* __restrict__ inp_pos, const int* __restrict__ inp_mask,
                const float* __restrict__ ws, float* __restrict__ out)
{
  __shared__ int cnt[PP];
  __shared__ int nr;
  int t = threadIdx.x;
  if (t < PP) cnt[t] = 0;
  if (t == 0) nr = 0;
  __syncthreads();
  int ln = 0;
  for (int n = t; n < NTOT; n += 256){
    int p = inp_pos[n];
    if (p < PP) atomicAdd(&cnt[p], 1);
    if (inp_mask[n] != 0 && (n & (LL-1)) != 0) ln++;
  }
  atomicAdd(&nr, ln);
  __syncthreads();
  if (t == 0){
    float ent = 0.f;
    for (int p = 0; p < PP; ++p){
      int c = cnt[p];
      if (c > 0){
        int denom = c * MM; if (denom < 1) denom = 1;
        ent = __fadd_rn(ent, __fdiv_rn(ws[p], (float)denom));
      }
    }
    out[OFF_ELOSS] = -ent;
    int nrc = nr; if (nrc < 1) nrc = 1;
    out[OFF_CLOSS] = -__fdiv_rn(ws[12], (float)nrc);
  }
}

// ---------- monolithic fallback (r2, proven) for tiny ws ----------
__global__ __launch_bounds__(256)
void row_kernel_mono(const float* __restrict__ ctx, const float* __restrict__ dec_W,
                const float* __restrict__ dec_b, const float* __restrict__ psr_w,
                const float* __restrict__ atk_w, const float* __restrict__ cW1,
                const float* __restrict__ cb1, const float* __restrict__ cW2,
                const float* __restrict__ cb2, const int* __restrict__ inp_word,
                const int* __restrict__ inp_pos, const int* __restrict__ inp_mask,
                const int* __restrict__ words, const int* __restrict__ lut,
                float* __restrict__ out, float* __restrict__ ws)
{
  const int n = blockIdx.x;
  const int t = threadIdx.x;

  __shared__ float  ctx_s[HSZ];
  __shared__ float  logit_s[MM];
  __shared__ float  h_s[64];
  __shared__ double redd[256];
  __shared__ float  redf[256];
  __shared__ int    redi[256];
  __shared__ float  sc[2];
  __shared__ int    si[1];

  for (int k = t; k < HSZ; k += 256) ctx_s[k] = ctx[(size_t)n*HSZ + k];
  __syncthreads();

  const int  pos   = inp_pos[n];
  const int  word  = inp_word[n];
  const int  msk   = inp_mask[n];
  const bool isobf = (pos < PP);
  const bool ispri = (pos < 4);

  if (t < 64){
    double acc = 0.0;
    for (int k = 0; k < HSZ; ++k) acc += (double)ctx_s[k] * (double)cW1[k*64 + t];
    float hv = __fadd_rn((float)acc, cb1[t]);
    h_s[t] = hv > 0.f ? hv : 0.f;
  }
  __syncthreads();

  if (t == 0){
    double a0 = 0.0, a1 = 0.0;
    for (int k = 0; k < 64; ++k){
      double hv = (double)h_s[k];
      a0 += hv * (double)cW2[k*2 + 0];
      a1 += hv * (double)cW2[k*2 + 1];
    }
    float senc, l21;
    gate_chain(n, pos, (float)a0, (float)a1, cb2, &senc, &l21);
    sc[0] = (senc < 0.f) ? -senc : 0.f;
    sc[1] = (senc < 0.f) ? 0.f : senc;
    if (msk != 0 && (n & (LL-1)) != 0) atomicAdd(ws + 12, l21);
  }

  if (isobf){
    const float4* W4 = (const float4*)(dec_W + (size_t)pos * HSZ * MM);
    double a0=0.0, a1=0.0, a2=0.0, a3=0.0;
    for (int k = 0; k < HSZ; ++k){
      double c = (double)ctx_s[k];
      float4 w = W4[(size_t)k*256 + t];
      a0 += c*(double)w.x; a1 += c*(double)w.y; a2 += c*(double)w.z; a3 += c*(double)w.w;
    }
    const float* bp = dec_b + (size_t)pos * MM;
    const int m0 = 4*t;
    logit_s[m0+0] = __fadd_rn((float)a0, bp[m0+0]);
    logit_s[m0+1] = __fadd_rn((float)a1, bp[m0+1]);
    logit_s[m0+2] = __fadd_rn((float)a2, bp[m0+2]);
    logit_s[m0+3] = __fadd_rn((float)a3, bp[m0+3]);
    __syncthreads();

    float lm = logit_s[m0];
    lm = fmaxf(lm, logit_s[m0+1]); lm = fmaxf(lm, logit_s[m0+2]); lm = fmaxf(lm, logit_s[m0+3]);
    redf[t] = lm; __syncthreads();
    for (int s = 128; s > 0; s >>= 1){ if (t < s) redf[t] = fmaxf(redf[t], redf[t+s]); __syncthreads(); }
    const float xmax = redf[0];
    __syncthreads();

    double dsm = 0.0;
    for (int j = 0; j < 4; ++j)
      dsm += (double)EXP32(__fsub_rn(logit_s[m0+j], xmax));
    redd[t] = dsm; __syncthreads();
    for (int s = 128; s > 0; s >>= 1){ if (t < s) redd[t] += redd[t+s]; __syncthreads(); }
    const float lse = LOG32((float)redd[0]);
    __syncthreads();

    unsigned kp0, kp1; tf2x32(0u, 42u, 0u, (unsigned)pos, kp0, kp1);
    float best = -3.4e38f; int bi = 0; double es = 0.0;
    for (int j = 0; j < 4; ++j){
      int m = m0 + j;
      float sh = __fsub_rn(logit_s[m], xmax);
      float lp = __fsub_rn(sh, lse);
      float ex = EXP32(lp);
      es += (double)__fmul_rn(-lp, ex);
      float g = gumbel_exact(tf_bits32(kp0, kp1, (unsigned)(n*MM + m)));
      float sv = __fadd_rn(lp, g);
      if (sv > best){ best = sv; bi = m; }
    }
    redf[t] = best; redi[t] = bi; redd[t] = es; __syncthreads();
    for (int s = 128; s > 0; s >>= 1){
      if (t < s){
        float v2 = redf[t+s]; int i2 = redi[t+s];
        if (v2 > redf[t] || (v2 == redf[t] && i2 < redi[t])){ redf[t] = v2; redi[t] = i2; }
        redd[t] += redd[t+s];
      }
      __syncthreads();
    }
    if (t == 0){ si[0] = redi[0]; atomicAdd(ws + pos, (float)redd[0]); }
    __syncthreads();
  } else {
    __syncthreads();
  }

  const int   idx = isobf ? si[0] : 0;
  const float c0 = sc[0], c1 = sc[1];
  const int   obf_word = isobf ? words[pos*MM + idx] : word;

  if (t == 0){
    float of = __fadd_rn(__fmul_rn((float)word, c0), __fmul_rn((float)obf_word, c1));
    int ow = (int)of;
    out[OFF_WORD + n] = (float)ow;
    bool cpym = (c0 == 1.0f) && (msk != 0);
    out[OFF_CPYM + n] = cpym ? 1.f : 0.f;
    out[OFF_OBFM + n] = (isobf && !cpym) ? 1.f : 0.f;
    out[OFF_PRIM + n] = ispri ? 1.f : 0.f;
    #pragma unroll
    for (int j = 0; j < CLEN; ++j)
      out[OFF_CHAR + (size_t)n*CLEN + j] = (float)lut[(size_t)ow*CLEN + j];
  }
  if (t < DD){
    float po = psr_w[(size_t)word*DD + t];
    float pb = isobf ? psr_w[(size_t)obf_word*DD + t] : po;
    out[OFF_PSR + (size_t)n*DD + t] = __fadd_rn(__fmul_rn(po, c0), __fmul_rn(pb, c1));
    float ao = atk_w[(size_t)word*DD + t];
    float ab = isobf ? atk_w[(size_t)obf_word*DD + t] : ao;
    out[OFF_ATK + (size_t)n*DD + t] = __fadd_rn(__fmul_rn(ao, c0), __fmul_rn(ab, c1));
  }
}

extern "C" void kernel_launch(void* const* d_in, const int* in_sizes, int n_in,
                              void* d_out, int out_size, void* d_ws, size_t ws_size,
                              hipStream_t stream)
{
  const float* ctx      = (const float*)d_in[0];
  const float* dec_W    = (const float*)d_in[1];
  const float* dec_b    = (const float*)d_in[2];
  const float* psr_w    = (const float*)d_in[3];
  const float* atk_w    = (const float*)d_in[4];
  const float* cW1      = (const float*)d_in[5];
  const float* cb1      = (const float*)d_in[6];
  const float* cW2      = (const float*)d_in[7];
  const float* cb2      = (const float*)d_in[8];
  const int*   inp_word = (const int*)d_in[9];
  const int*   inp_pos  = (const int*)d_in[10];
  const int*   inp_mask = (const int*)d_in[11];
  const int*   words    = (const int*)d_in[12];
  const int*   lut      = (const int*)d_in[13];
  float* out = (float*)d_out;
  float* ws  = (float*)d_ws;

  const size_t need = ((size_t)WS_LOGITS_OFF + (size_t)NTOT*MM) * 4;

  if (ws_size >= need){
    int*   cntg      = (int*)ws + 16;
    int*   rowlist   = (int*)ws + 64;
    float* scbuf     = ws + WS_SC_OFF;
    float* logitsbuf = ws + WS_LOGITS_OFF;
    bucket_kernel<<<PP, 256, 0, stream>>>(inp_pos, cntg, rowlist);
    cpy_build_kernel<<<NTOT/CPB, 256, 0, stream>>>(ctx, cW1, cb1, cW2, cb2,
                                                   inp_pos, scbuf);
    gemm_kernel<<<dim3(MM/CT, LISTCAP/RT, PP), 256, 0, stream>>>(ctx, dec_W, cntg,
                                                                 rowlist, logitsbuf);
    finalize_kernel<<<NTOT/4, 256, 0, stream>>>(dec_b, psr_w, atk_w,
                                                inp_word, inp_pos, inp_mask, words, lut,
                                                logitsbuf, scbuf, out);
    fin2_kernel<<<1, 1024, 0, stream>>>(inp_pos, inp_mask, scbuf, logitsbuf, out);
  } else {
    hipMemsetAsync(ws, 0, 512, stream);
    row_kernel_mono<<<NTOT, 256, 0, stream>>>(ctx, dec_W, dec_b, psr_w, atk_w,
                                              cW1, cb1, cW2, cb2,
                                              inp_word, inp_pos, inp_mask, words, lut,
                                              out, ws);
    fin_kernel<<<1, 256, 0, stream>>>(inp_pos, inp_mask, ws, out);
  }
}